// Round 2
// baseline (252.006 us; speedup 1.0000x reference)
//
#include <hip/hip_runtime.h>
#include <hip/hip_bf16.h>
#include <cstdint>
#include <cstddef>

typedef __bf16 bf16x8 __attribute__((ext_vector_type(8)));
typedef float f32x4 __attribute__((ext_vector_type(4)));
typedef unsigned int u32x4 __attribute__((ext_vector_type(4)));

union U16x8 {
  u32x4 u;
  bf16x8 b;
  unsigned short s[8];
  ushort4 q[2];
};

__device__ __forceinline__ unsigned short f2bf(float f) {
  union { float f; unsigned u; } v;
  v.f = f;
  unsigned r = v.u + 0x7FFFu + ((v.u >> 16) & 1u);
  return (unsigned short)(r >> 16);
}

__device__ __forceinline__ unsigned pack_bf2(float a, float b) {
  return (unsigned)f2bf(a) | ((unsigned)f2bf(b) << 16);
}

// ---------------- weight prep: f32 -> bf16, transposed to [N][K] ----------------
__global__ __launch_bounds__(256) void prep_weights(
    const float* __restrict__ Wqkv, const float* __restrict__ Wout,
    const float* __restrict__ Wf1, const float* __restrict__ Wf2,
    unsigned short* __restrict__ qkv_t, unsigned short* __restrict__ out_t,
    unsigned short* __restrict__ f1_t, unsigned short* __restrict__ f2_t) {
  int i = blockIdx.x * 256 + threadIdx.x;
  if (i < 768 * 256) { int n = i >> 8, k = i & 255; qkv_t[i] = f2bf(Wqkv[k * 768 + n]); return; }
  i -= 768 * 256;
  if (i < 256 * 256) { int n = i >> 8, k = i & 255; out_t[i] = f2bf(Wout[k * 256 + n]); return; }
  i -= 256 * 256;
  if (i < 512 * 256) { int n = i >> 8, k = i & 255; f1_t[i] = f2bf(Wf1[k * 512 + n]); return; }
  i -= 512 * 256;
  if (i < 256 * 512) { int n = i >> 9, k = i & 511; f2_t[i] = f2bf(Wf2[k * 256 + n]); return; }
}

// ---------------- LayerNorm (f32 in -> bf16 out), 1 wave per 256-wide row ----------------
__global__ __launch_bounds__(256) void ln_kernel(
    const float* __restrict__ x, const float* __restrict__ gw, const float* __restrict__ bw,
    unsigned short* __restrict__ out) {
  const int row = blockIdx.x * 4 + (threadIdx.x >> 6);
  const int lane = threadIdx.x & 63;
  const float4 v = *reinterpret_cast<const float4*>(x + (size_t)row * 256 + lane * 4);
  float s = v.x + v.y + v.z + v.w;
  float s2 = v.x * v.x + v.y * v.y + v.z * v.z + v.w * v.w;
#pragma unroll
  for (int m = 1; m < 64; m <<= 1) {
    s += __shfl_xor(s, m);
    s2 += __shfl_xor(s2, m);
  }
  const float mean = s * (1.f / 256.f);
  const float var = s2 * (1.f / 256.f) - mean * mean;
  const float rstd = rsqrtf(var + 1e-5f);
  const float4 gg = *reinterpret_cast<const float4*>(gw + lane * 4);
  const float4 bb = *reinterpret_cast<const float4*>(bw + lane * 4);
  ushort4 o;
  o.x = f2bf((v.x - mean) * rstd * gg.x + bb.x);
  o.y = f2bf((v.y - mean) * rstd * gg.y + bb.y);
  o.z = f2bf((v.z - mean) * rstd * gg.z + bb.z);
  o.w = f2bf((v.w - mean) * rstd * gg.w + bb.w);
  *reinterpret_cast<ushort4*>(out + (size_t)row * 256 + lane * 4) = o;
}

// ---------------- direct-global MFMA GEMM: C[M][N] = A[M][K](bf16) @ Wt[N][K](bf16)^T ----------------
template <int EPI, int K, int N>
__global__ __launch_bounds__(256) void gemm_kernel(
    const unsigned short* __restrict__ A, const unsigned short* __restrict__ Wt,
    const float* __restrict__ bias, const float* __restrict__ res, void* __restrict__ outp) {
  const int w = threadIdx.x >> 6;
  const int lane = threadIdx.x & 63;
  const int l15 = lane & 15;
  const int g = lane >> 4;
  const int m0 = blockIdx.x * 128 + w * 32;
  const int n0 = blockIdx.y * 64;

  f32x4 acc[2][4];
#pragma unroll
  for (int mf = 0; mf < 2; ++mf)
#pragma unroll
    for (int nf = 0; nf < 4; ++nf) acc[mf][nf] = f32x4{0.f, 0.f, 0.f, 0.f};

#pragma unroll 4
  for (int kk = 0; kk < K / 32; ++kk) {
    U16x8 a[2], bfr[4];
#pragma unroll
    for (int mf = 0; mf < 2; ++mf)
      a[mf].u = *reinterpret_cast<const u32x4*>(A + (size_t)(m0 + mf * 16 + l15) * K + kk * 32 + g * 8);
#pragma unroll
    for (int nf = 0; nf < 4; ++nf)
      bfr[nf].u = *reinterpret_cast<const u32x4*>(Wt + (size_t)(n0 + nf * 16 + l15) * K + kk * 32 + g * 8);
#pragma unroll
    for (int mf = 0; mf < 2; ++mf)
#pragma unroll
      for (int nf = 0; nf < 4; ++nf)
        acc[mf][nf] = __builtin_amdgcn_mfma_f32_16x16x32_bf16(a[mf].b, bfr[nf].b, acc[mf][nf], 0, 0, 0);
  }

#pragma unroll
  for (int mf = 0; mf < 2; ++mf)
#pragma unroll
    for (int nf = 0; nf < 4; ++nf)
#pragma unroll
      for (int r = 0; r < 4; ++r) {
        const int m = m0 + mf * 16 + g * 4 + r;
        const int n = n0 + nf * 16 + l15;
        float v = acc[mf][nf][r] + bias[n];
        if constexpr (EPI == 1) {
          v += res[(size_t)m * 256 + n];
          reinterpret_cast<float*>(outp)[(size_t)m * 256 + n] = v;
        } else if constexpr (EPI == 2) {
          v = 0.5f * v * (1.0f + erff(v * 0.70710678118654752f));
          reinterpret_cast<unsigned short*>(outp)[(size_t)m * N + n] = f2bf(v);
        } else {
          reinterpret_cast<unsigned short*>(outp)[(size_t)m * N + n] = f2bf(v);
        }
      }
}

// ---------------- V transpose: qkv[:,512:768] (per b,h: [c][dk]) -> vt [b][h][dk][c] ----------------
__global__ __launch_bounds__(256) void transpose_v(
    const unsigned short* __restrict__ qkv, unsigned short* __restrict__ vt) {
  __shared__ unsigned short tile[64][40];
  const int t = threadIdx.x;
  const int ct = blockIdx.x & 31;
  const int h = (blockIdx.x >> 5) & 7;
  const int b = blockIdx.x >> 8;
  {
    const int c = t >> 2;
    const int dkb = (t & 3) * 8;
    U16x8 v;
    v.u = *reinterpret_cast<const u32x4*>(qkv + (size_t)(b * 2048 + ct * 64 + c) * 768 + 512 + h * 32 + dkb);
#pragma unroll
    for (int j = 0; j < 8; ++j) tile[c][dkb + j] = v.s[j];
  }
  __syncthreads();
  {
    const int dk = t >> 3;
    const int cb = (t & 7) * 8;
    U16x8 v;
#pragma unroll
    for (int j = 0; j < 8; ++j) v.s[j] = tile[cb + j][dk];
    *reinterpret_cast<u32x4*>(vt + (size_t)((b * 8 + h) * 32 + dk) * 2048 + ct * 64 + cb) = v.u;
  }
}

// ---------------- flash attention, swapped-operand QK^T ----------------
// block = (b, 16-row q-tile), wave = head. S^T = mfma(K, Q): lane (g,l15) holds
// S[k=kv0+f*16+g*4+r][q=q0+l15] -> softmax over k is lane-local + shfl_xor(16,32).
__global__ __launch_bounds__(512, 4) void attn_kernel(
    const unsigned short* __restrict__ qkv, const unsigned short* __restrict__ vt,
    const float* __restrict__ adj, unsigned short* __restrict__ out) {
  // per-wave P^T staging: 16 q-rows x 64 k, rows padded to 68 halfs (b64 ops land
  // at the 4-lane/bank floor -> conflict-optimal)
  __shared__ __align__(16) unsigned short pt_lds[8][16 * 68];
  const int h = threadIdx.x >> 6;
  const int lane = threadIdx.x & 63;
  const int l15 = lane & 15;
  const int g = lane >> 4;
  const int q0 = blockIdx.x * 16;
  const int b = blockIdx.y;
  const float scale = 0.17677669529663689f;  // 1/sqrt(32)

  unsigned short* pt = &pt_lds[h][0];

  // Q as B-operand: lane holds Q[q0+l15][g*8+j], j=0..7 (one frag covers dk=32)
  U16x8 qa;
  qa.u = *reinterpret_cast<const u32x4*>(qkv + (size_t)(b * 2048 + q0 + l15) * 768 + h * 32 + g * 8);

  f32x4 o[2];
  o[0] = f32x4{0.f, 0.f, 0.f, 0.f};
  o[1] = f32x4{0.f, 0.f, 0.f, 0.f};
  float mrun = -1e30f, lrun = 0.f;

  const float* bptr = adj + ((size_t)b * 2048 + q0 + l15) * 2048;
  const unsigned short* kbase = qkv + (size_t)(b * 2048) * 768 + 256 + h * 32 + g * 8;
  const unsigned short* vbase0 = vt + (size_t)((b * 8 + h) * 32 + l15) * 2048 + g * 8;
  const unsigned short* vbase1 = vt + (size_t)((b * 8 + h) * 32 + 16 + l15) * 2048 + g * 8;

  for (int kt = 0; kt < 32; ++kt) {
    const int kv0 = kt * 64;

    // K as A-operand: kb[f] = K[kv0+f*16+l15][g*8+j]
    U16x8 kb[4];
#pragma unroll
    for (int f = 0; f < 4; ++f)
      kb[f].u = *reinterpret_cast<const u32x4*>(kbase + (size_t)(kv0 + f * 16 + l15) * 768);

    // adj as float4: lane (g,l15) needs rows' cols kv0+f*16+g*4..+3 of q-row l15
    f32x4 adjv[4];
#pragma unroll
    for (int f = 0; f < 4; ++f)
      adjv[f] = *reinterpret_cast<const f32x4*>(bptr + kv0 + f * 16 + g * 4);

    f32x4 s[4];
    const f32x4 z = {0.f, 0.f, 0.f, 0.f};
#pragma unroll
    for (int f = 0; f < 4; ++f)
      s[f] = __builtin_amdgcn_mfma_f32_16x16x32_bf16(kb[f].b, qa.b, z, 0, 0, 0);
#pragma unroll
    for (int f = 0; f < 4; ++f)
#pragma unroll
      for (int r = 0; r < 4; ++r) s[f][r] = fmaf(s[f][r], scale, adjv[f][r]);

    // tile max over the 16 lane-local values + cross-g reduce
    float mx = s[0][0];
#pragma unroll
    for (int f = 0; f < 4; ++f)
#pragma unroll
      for (int r = 0; r < 4; ++r) mx = fmaxf(mx, s[f][r]);
    mx = fmaxf(mx, __shfl_xor(mx, 16));
    mx = fmaxf(mx, __shfl_xor(mx, 32));

    // defer-max (T13): only rescale O when max grows by >8
    if (!__all(mx <= mrun + 8.f)) {
      const float mnew = fmaxf(mrun, mx);
      const float alpha = __expf(mrun - mnew);
      mrun = mnew;
      lrun *= alpha;
#pragma unroll
      for (int r = 0; r < 4; ++r) {
        const float ao = __shfl(alpha, g * 4 + r);  // O rows are q=g*4+r; alpha lives at lane l15=q
        o[0][r] *= ao;
        o[1][r] *= ao;
      }
    }

    float rs = 0.f;
#pragma unroll
    for (int f = 0; f < 4; ++f)
#pragma unroll
      for (int r = 0; r < 4; ++r) {
        const float p = __expf(s[f][r] - mrun);
        s[f][r] = p;
        rs += p;
      }
    rs += __shfl_xor(rs, 16);
    rs += __shfl_xor(rs, 32);
    lrun += rs;

    // P -> LDS, vectorized b64 writes: row q=l15, cols f*16+g*4..+3
#pragma unroll
    for (int f = 0; f < 4; ++f) {
      uint2 pk;
      pk.x = pack_bf2(s[f][0], s[f][1]);
      pk.y = pack_bf2(s[f][2], s[f][3]);
      *reinterpret_cast<uint2*>(&pt[l15 * 68 + f * 16 + g * 4]) = pk;
    }

    // PV: A = P[q=l15][k=kf*32+g*8+j] (two b64 reads), B = V via vt (b128 global)
    U16x8 pa[2], vb[2][2];
#pragma unroll
    for (int kf = 0; kf < 2; ++kf) {
      pa[kf].q[0] = *reinterpret_cast<const ushort4*>(&pt[l15 * 68 + kf * 32 + g * 8]);
      pa[kf].q[1] = *reinterpret_cast<const ushort4*>(&pt[l15 * 68 + kf * 32 + g * 8 + 4]);
    }
#pragma unroll
    for (int kf = 0; kf < 2; ++kf) {
      vb[kf][0].u = *reinterpret_cast<const u32x4*>(vbase0 + kv0 + kf * 32);
      vb[kf][1].u = *reinterpret_cast<const u32x4*>(vbase1 + kv0 + kf * 32);
    }
#pragma unroll
    for (int n = 0; n < 2; ++n)
#pragma unroll
      for (int kf = 0; kf < 2; ++kf)
        o[n] = __builtin_amdgcn_mfma_f32_16x16x32_bf16(pa[kf].b, vb[kf][n].b, o[n], 0, 0, 0);
  }

#pragma unroll
  for (int r = 0; r < 4; ++r) {
    const float linv = 1.0f / __shfl(lrun, g * 4 + r);
#pragma unroll
    for (int n = 0; n < 2; ++n)
      out[(size_t)(b * 2048 + q0 + g * 4 + r) * 256 + h * 32 + n * 16 + l15] =
          f2bf(o[n][r] * linv);
  }
}

extern "C" void kernel_launch(void* const* d_in, const int* in_sizes, int n_in,
                              void* d_out, int out_size, void* d_ws, size_t ws_size,
                              hipStream_t stream) {
  const float* h_in  = (const float*)d_in[0];
  const float* adj   = (const float*)d_in[1];
  const float* Wqkv  = (const float*)d_in[2];
  const float* bqkv  = (const float*)d_in[3];
  const float* Wout  = (const float*)d_in[4];
  const float* bout  = (const float*)d_in[5];
  const float* g1    = (const float*)d_in[6];
  const float* beta1 = (const float*)d_in[7];
  const float* g2    = (const float*)d_in[8];
  const float* beta2 = (const float*)d_in[9];
  const float* Wf1   = (const float*)d_in[10];
  const float* bf1   = (const float*)d_in[11];
  const float* Wf2   = (const float*)d_in[12];
  const float* bf2   = (const float*)d_in[13];

  char* ws = (char*)d_ws;
  unsigned short* wqkv_t = (unsigned short*)(ws);
  unsigned short* wout_t = (unsigned short*)(ws + 393216);
  unsigned short* wf1_t  = (unsigned short*)(ws + 524288);
  unsigned short* wf2_t  = (unsigned short*)(ws + 786432);
  size_t off = 1048576;
  unsigned short* h_n    = (unsigned short*)(ws + off); off += (size_t)8192 * 256 * 2;
  unsigned short* qkv    = (unsigned short*)(ws + off); off += (size_t)8192 * 768 * 2;
  unsigned short* vtb    = (unsigned short*)(ws + off); off += (size_t)1024 * 2048 * 2;
  unsigned short* attn_o = (unsigned short*)(ws + off); off += (size_t)8192 * 256 * 2;
  float*          h_mid  = (float*)(ws + off);          off += (size_t)8192 * 256 * 4;
  unsigned short* h2     = (unsigned short*)(ws + off); off += (size_t)8192 * 256 * 2;
  unsigned short* a1     = (unsigned short*)(ws + off); off += (size_t)8192 * 512 * 2;

  prep_weights<<<2048, 256, 0, stream>>>(Wqkv, Wout, Wf1, Wf2, wqkv_t, wout_t, wf1_t, wf2_t);
  ln_kernel<<<2048, 256, 0, stream>>>(h_in, g1, beta1, h_n);
  gemm_kernel<0, 256, 768><<<dim3(64, 12), 256, 0, stream>>>(h_n, wqkv_t, bqkv, nullptr, qkv);
  transpose_v<<<1024, 256, 0, stream>>>(qkv, vtb);
  attn_kernel<<<dim3(128, 4), 512, 0, stream>>>(qkv, vtb, adj, attn_o);
  gemm_kernel<1, 256, 256><<<dim3(64, 4), 256, 0, stream>>>(attn_o, wout_t, bout, h_in, h_mid);
  ln_kernel<<<2048, 256, 0, stream>>>(h_mid, g2, beta2, h2);
  gemm_kernel<2, 256, 512><<<dim3(64, 8), 256, 0, stream>>>(h2, wf1_t, bf1, nullptr, a1);
  gemm_kernel<1, 512, 256><<<dim3(64, 4), 256, 0, stream>>>(a1, wf2_t, bf2, h_mid, (float*)d_out);
}

// Round 3
// 199.621 us; speedup vs baseline: 1.2624x; 1.2624x over previous
//
#include <hip/hip_runtime.h>
#include <hip/hip_bf16.h>
#include <cstdint>
#include <cstddef>

typedef __bf16 bf16x8 __attribute__((ext_vector_type(8)));
typedef float f32x4 __attribute__((ext_vector_type(4)));
typedef unsigned int u32x4 __attribute__((ext_vector_type(4)));

union U16x8 {
  u32x4 u;
  bf16x8 b;
  unsigned short s[8];
  ushort4 q[2];
};

__device__ __forceinline__ unsigned short f2bf(float f) {
  union { float f; unsigned u; } v;
  v.f = f;
  unsigned r = v.u + 0x7FFFu + ((v.u >> 16) & 1u);
  return (unsigned short)(r >> 16);
}

__device__ __forceinline__ unsigned pack2(float a, float b) {
  __hip_bfloat162 t = __float22bfloat162_rn(make_float2(a, b));
  return *reinterpret_cast<unsigned*>(&t);  // low16 = bf(a), high16 = bf(b)
}

// ---------------- weight prep: f32 -> bf16, transposed to [N][K] ----------------
__global__ __launch_bounds__(256) void prep_weights(
    const float* __restrict__ Wqkv, const float* __restrict__ Wout,
    const float* __restrict__ Wf1, const float* __restrict__ Wf2,
    unsigned short* __restrict__ qkv_t, unsigned short* __restrict__ out_t,
    unsigned short* __restrict__ f1_t, unsigned short* __restrict__ f2_t) {
  int i = blockIdx.x * 256 + threadIdx.x;
  if (i < 768 * 256) { int n = i >> 8, k = i & 255; qkv_t[i] = f2bf(Wqkv[k * 768 + n]); return; }
  i -= 768 * 256;
  if (i < 256 * 256) { int n = i >> 8, k = i & 255; out_t[i] = f2bf(Wout[k * 256 + n]); return; }
  i -= 256 * 256;
  if (i < 512 * 256) { int n = i >> 8, k = i & 255; f1_t[i] = f2bf(Wf1[k * 512 + n]); return; }
  i -= 512 * 256;
  if (i < 256 * 512) { int n = i >> 9, k = i & 511; f2_t[i] = f2bf(Wf2[k * 256 + n]); return; }
}

// ---------------- LayerNorm (f32 in -> bf16 out), 1 wave per 256-wide row ----------------
__global__ __launch_bounds__(256) void ln_kernel(
    const float* __restrict__ x, const float* __restrict__ gw, const float* __restrict__ bw,
    unsigned short* __restrict__ out) {
  const int row = blockIdx.x * 4 + (threadIdx.x >> 6);
  const int lane = threadIdx.x & 63;
  const float4 v = *reinterpret_cast<const float4*>(x + (size_t)row * 256 + lane * 4);
  float s = v.x + v.y + v.z + v.w;
  float s2 = v.x * v.x + v.y * v.y + v.z * v.z + v.w * v.w;
#pragma unroll
  for (int m = 1; m < 64; m <<= 1) {
    s += __shfl_xor(s, m);
    s2 += __shfl_xor(s2, m);
  }
  const float mean = s * (1.f / 256.f);
  const float var = s2 * (1.f / 256.f) - mean * mean;
  const float rstd = rsqrtf(var + 1e-5f);
  const float4 gg = *reinterpret_cast<const float4*>(gw + lane * 4);
  const float4 bb = *reinterpret_cast<const float4*>(bw + lane * 4);
  ushort4 o;
  o.x = f2bf((v.x - mean) * rstd * gg.x + bb.x);
  o.y = f2bf((v.y - mean) * rstd * gg.y + bb.y);
  o.z = f2bf((v.z - mean) * rstd * gg.z + bb.z);
  o.w = f2bf((v.w - mean) * rstd * gg.w + bb.w);
  *reinterpret_cast<ushort4*>(out + (size_t)row * 256 + lane * 4) = o;
}

// ---------------- direct-global MFMA GEMM: C[M][N] = A[M][K](bf16) @ Wt[N][K](bf16)^T ----------------
template <int EPI, int K, int N>
__global__ __launch_bounds__(256) void gemm_kernel(
    const unsigned short* __restrict__ A, const unsigned short* __restrict__ Wt,
    const float* __restrict__ bias, const float* __restrict__ res, void* __restrict__ outp) {
  const int w = threadIdx.x >> 6;
  const int lane = threadIdx.x & 63;
  const int l15 = lane & 15;
  const int g = lane >> 4;
  const int m0 = blockIdx.x * 128 + w * 32;
  const int n0 = blockIdx.y * 64;

  f32x4 acc[2][4];
#pragma unroll
  for (int mf = 0; mf < 2; ++mf)
#pragma unroll
    for (int nf = 0; nf < 4; ++nf) acc[mf][nf] = f32x4{0.f, 0.f, 0.f, 0.f};

#pragma unroll 4
  for (int kk = 0; kk < K / 32; ++kk) {
    U16x8 a[2], bfr[4];
#pragma unroll
    for (int mf = 0; mf < 2; ++mf)
      a[mf].u = *reinterpret_cast<const u32x4*>(A + (size_t)(m0 + mf * 16 + l15) * K + kk * 32 + g * 8);
#pragma unroll
    for (int nf = 0; nf < 4; ++nf)
      bfr[nf].u = *reinterpret_cast<const u32x4*>(Wt + (size_t)(n0 + nf * 16 + l15) * K + kk * 32 + g * 8);
#pragma unroll
    for (int mf = 0; mf < 2; ++mf)
#pragma unroll
      for (int nf = 0; nf < 4; ++nf)
        acc[mf][nf] = __builtin_amdgcn_mfma_f32_16x16x32_bf16(a[mf].b, bfr[nf].b, acc[mf][nf], 0, 0, 0);
  }

#pragma unroll
  for (int mf = 0; mf < 2; ++mf)
#pragma unroll
    for (int nf = 0; nf < 4; ++nf)
#pragma unroll
      for (int r = 0; r < 4; ++r) {
        const int m = m0 + mf * 16 + g * 4 + r;
        const int n = n0 + nf * 16 + l15;
        float v = acc[mf][nf][r] + bias[n];
        if constexpr (EPI == 1) {
          v += res[(size_t)m * 256 + n];
          reinterpret_cast<float*>(outp)[(size_t)m * 256 + n] = v;
        } else if constexpr (EPI == 2) {
          v = 0.5f * v * (1.0f + erff(v * 0.70710678118654752f));
          reinterpret_cast<unsigned short*>(outp)[(size_t)m * N + n] = f2bf(v);
        } else {
          reinterpret_cast<unsigned short*>(outp)[(size_t)m * N + n] = f2bf(v);
        }
      }
}

// ---------------- V transpose: qkv[:,512:768] (per b,h: [c][dk]) -> vt [b][h][dk][c] ----------------
__global__ __launch_bounds__(256) void transpose_v(
    const unsigned short* __restrict__ qkv, unsigned short* __restrict__ vt) {
  __shared__ unsigned short tile[64][40];
  const int t = threadIdx.x;
  const int ct = blockIdx.x & 31;
  const int h = (blockIdx.x >> 5) & 7;
  const int b = blockIdx.x >> 8;
  {
    const int c = t >> 2;
    const int dkb = (t & 3) * 8;
    U16x8 v;
    v.u = *reinterpret_cast<const u32x4*>(qkv + (size_t)(b * 2048 + ct * 64 + c) * 768 + 512 + h * 32 + dkb);
#pragma unroll
    for (int j = 0; j < 8; ++j) tile[c][dkb + j] = v.s[j];
  }
  __syncthreads();
  {
    const int dk = t >> 3;
    const int cb = (t & 7) * 8;
    U16x8 v;
#pragma unroll
    for (int j = 0; j < 8; ++j) v.s[j] = tile[cb + j][dk];
    *reinterpret_cast<u32x4*>(vt + (size_t)((b * 8 + h) * 32 + dk) * 2048 + ct * 64 + cb) = v.u;
  }
}

// ---------------- flash attention, swapped-operand QK^T, QBLK=32, prefetched ----------------
// block = (b, 32-row q-tile), wave = head. S^T = mfma(K, Q): lane (g,l15) holds
// S[k=kv0+f*16+g*4+r][q=q0+qf*16+l15] -> softmax over k is lane-local + shfl_xor(16,32).
// K[t+1], adj[t+1] register-double-buffered; issued before iter-t compute.
__global__ __launch_bounds__(512) void attn_kernel(
    const unsigned short* __restrict__ qkv, const unsigned short* __restrict__ vt,
    const float* __restrict__ adj, unsigned short* __restrict__ out) {
  __shared__ __align__(16) unsigned short pt_lds[8][2][16 * 68];
  const int h = threadIdx.x >> 6;
  const int lane = threadIdx.x & 63;
  const int l15 = lane & 15;
  const int g = lane >> 4;
  const int q0 = blockIdx.x * 32;
  const int b = blockIdx.y;
  const float scale = 0.17677669529663689f;  // 1/sqrt(32)

  unsigned short* pt[2] = {&pt_lds[h][0][0], &pt_lds[h][1][0]};

  // Q as B-operand: lane holds Q[q0+qf*16+l15][g*8+j]
  U16x8 qa[2];
#pragma unroll
  for (int qf = 0; qf < 2; ++qf)
    qa[qf].u = *reinterpret_cast<const u32x4*>(
        qkv + (size_t)(b * 2048 + q0 + qf * 16 + l15) * 768 + h * 32 + g * 8);

  f32x4 o[2][2];
#pragma unroll
  for (int qf = 0; qf < 2; ++qf) {
    o[qf][0] = f32x4{0.f, 0.f, 0.f, 0.f};
    o[qf][1] = f32x4{0.f, 0.f, 0.f, 0.f};
  }
  float mrun[2] = {-1e30f, -1e30f};
  float lrun[2] = {0.f, 0.f};

  const float* bptr[2];
  bptr[0] = adj + ((size_t)b * 2048 + q0 + l15) * 2048;
  bptr[1] = bptr[0] + (size_t)16 * 2048;
  const unsigned short* kbase = qkv + (size_t)(b * 2048) * 768 + 256 + h * 32 + g * 8;
  const unsigned short* vbase0 = vt + (size_t)((b * 8 + h) * 32 + l15) * 2048 + g * 8;
  const unsigned short* vbase1 = vt + (size_t)((b * 8 + h) * 32 + 16 + l15) * 2048 + g * 8;

  // double-buffered K frags + adj
  U16x8 kb[2][4];
  f32x4 adjv[2][2][4];
#pragma unroll
  for (int f = 0; f < 4; ++f)
    kb[0][f].u = *reinterpret_cast<const u32x4*>(kbase + (size_t)(f * 16 + l15) * 768);
#pragma unroll
  for (int qf = 0; qf < 2; ++qf)
#pragma unroll
    for (int f = 0; f < 4; ++f)
      adjv[0][qf][f] = *reinterpret_cast<const f32x4*>(bptr[qf] + f * 16 + g * 4);

#pragma unroll 2
  for (int kt = 0; kt < 32; ++kt) {
    const int cur = kt & 1;
    const int nxt = cur ^ 1;
    const int kv0 = kt * 64;

    // V for current iter (used at bottom -> full-iteration overlap)
    U16x8 vb[2][2];
#pragma unroll
    for (int kf = 0; kf < 2; ++kf) {
      vb[kf][0].u = *reinterpret_cast<const u32x4*>(vbase0 + kv0 + kf * 32);
      vb[kf][1].u = *reinterpret_cast<const u32x4*>(vbase1 + kv0 + kf * 32);
    }
    // prefetch next-iter K + adj (no wait until next iteration's use)
    if (kt < 31) {
#pragma unroll
      for (int f = 0; f < 4; ++f)
        kb[nxt][f].u = *reinterpret_cast<const u32x4*>(kbase + (size_t)(kv0 + 64 + f * 16 + l15) * 768);
#pragma unroll
      for (int qf = 0; qf < 2; ++qf)
#pragma unroll
        for (int f = 0; f < 4; ++f)
          adjv[nxt][qf][f] = *reinterpret_cast<const f32x4*>(bptr[qf] + kv0 + 64 + f * 16 + g * 4);
    }

    f32x4 s[2][4];
    const f32x4 z = {0.f, 0.f, 0.f, 0.f};
#pragma unroll
    for (int qf = 0; qf < 2; ++qf)
#pragma unroll
      for (int f = 0; f < 4; ++f)
        s[qf][f] = __builtin_amdgcn_mfma_f32_16x16x32_bf16(kb[cur][f].b, qa[qf].b, z, 0, 0, 0);
#pragma unroll
    for (int qf = 0; qf < 2; ++qf)
#pragma unroll
      for (int f = 0; f < 4; ++f)
#pragma unroll
        for (int r = 0; r < 4; ++r)
          s[qf][f][r] = fmaf(s[qf][f][r], scale, adjv[cur][qf][f][r]);

    // per-q max (lane-local 16 values) + cross-g reduce
    float mx[2];
#pragma unroll
    for (int qf = 0; qf < 2; ++qf) {
      float m01 = fmaxf(fmaxf(s[qf][0][0], s[qf][0][1]), fmaxf(s[qf][0][2], s[qf][0][3]));
      float m23 = fmaxf(fmaxf(s[qf][1][0], s[qf][1][1]), fmaxf(s[qf][1][2], s[qf][1][3]));
      float m45 = fmaxf(fmaxf(s[qf][2][0], s[qf][2][1]), fmaxf(s[qf][2][2], s[qf][2][3]));
      float m67 = fmaxf(fmaxf(s[qf][3][0], s[qf][3][1]), fmaxf(s[qf][3][2], s[qf][3][3]));
      float m = fmaxf(fmaxf(m01, m23), fmaxf(m45, m67));
      m = fmaxf(m, __shfl_xor(m, 16));
      m = fmaxf(m, __shfl_xor(m, 32));
      mx[qf] = m;
    }

    // defer-max (T13): rescale O only when max grows by >8
    const int ok = (mx[0] <= mrun[0] + 8.f) && (mx[1] <= mrun[1] + 8.f);
    if (!__all(ok)) {
#pragma unroll
      for (int qf = 0; qf < 2; ++qf) {
        const float mnew = fmaxf(mrun[qf], mx[qf]);
        const float alpha = __expf(mrun[qf] - mnew);
        mrun[qf] = mnew;
        lrun[qf] *= alpha;
#pragma unroll
        for (int r = 0; r < 4; ++r) {
          const float ao = __shfl(alpha, g * 4 + r);  // alpha lives at lane l15=q (uniform in g)
          o[qf][0][r] *= ao;
          o[qf][1][r] *= ao;
        }
      }
    }

#pragma unroll
    for (int qf = 0; qf < 2; ++qf) {
      float rs0 = 0.f, rs1 = 0.f, rs2 = 0.f, rs3 = 0.f;
#pragma unroll
      for (int f = 0; f < 4; ++f) {
        const float p0 = __expf(s[qf][f][0] - mrun[qf]);
        const float p1 = __expf(s[qf][f][1] - mrun[qf]);
        const float p2 = __expf(s[qf][f][2] - mrun[qf]);
        const float p3 = __expf(s[qf][f][3] - mrun[qf]);
        s[qf][f][0] = p0; s[qf][f][1] = p1; s[qf][f][2] = p2; s[qf][f][3] = p3;
        rs0 += p0; rs1 += p1; rs2 += p2; rs3 += p3;
      }
      float rs = (rs0 + rs1) + (rs2 + rs3);
      rs += __shfl_xor(rs, 16);
      rs += __shfl_xor(rs, 32);
      lrun[qf] += rs;
    }

    // P -> LDS (b64 writes, row q=l15 padded to 68 halfs; b64 lands at free 2-way/phase)
#pragma unroll
    for (int qf = 0; qf < 2; ++qf)
#pragma unroll
      for (int f = 0; f < 4; ++f) {
        uint2 pk;
        pk.x = pack2(s[qf][f][0], s[qf][f][1]);
        pk.y = pack2(s[qf][f][2], s[qf][f][3]);
        *reinterpret_cast<uint2*>(&pt[qf][l15 * 68 + f * 16 + g * 4]) = pk;
      }

    // P A-frags from LDS, PV accumulate
    U16x8 pa[2][2];
#pragma unroll
    for (int qf = 0; qf < 2; ++qf)
#pragma unroll
      for (int kf = 0; kf < 2; ++kf) {
        pa[qf][kf].q[0] = *reinterpret_cast<const ushort4*>(&pt[qf][l15 * 68 + kf * 32 + g * 8]);
        pa[qf][kf].q[1] = *reinterpret_cast<const ushort4*>(&pt[qf][l15 * 68 + kf * 32 + g * 8 + 4]);
      }
#pragma unroll
    for (int qf = 0; qf < 2; ++qf)
#pragma unroll
      for (int n = 0; n < 2; ++n)
#pragma unroll
        for (int kf = 0; kf < 2; ++kf)
          o[qf][n] = __builtin_amdgcn_mfma_f32_16x16x32_bf16(pa[qf][kf].b, vb[kf][n].b, o[qf][n], 0, 0, 0);
  }

#pragma unroll
  for (int qf = 0; qf < 2; ++qf)
#pragma unroll
    for (int r = 0; r < 4; ++r) {
      const float linv = 1.0f / __shfl(lrun[qf], g * 4 + r);
#pragma unroll
      for (int n = 0; n < 2; ++n)
        out[(size_t)(b * 2048 + q0 + qf * 16 + g * 4 + r) * 256 + h * 32 + n * 16 + l15] =
            f2bf(o[qf][n][r] * linv);
    }
}

extern "C" void kernel_launch(void* const* d_in, const int* in_sizes, int n_in,
                              void* d_out, int out_size, void* d_ws, size_t ws_size,
                              hipStream_t stream) {
  const float* h_in  = (const float*)d_in[0];
  const float* adj   = (const float*)d_in[1];
  const float* Wqkv  = (const float*)d_in[2];
  const float* bqkv  = (const float*)d_in[3];
  const float* Wout  = (const float*)d_in[4];
  const float* bout  = (const float*)d_in[5];
  const float* g1    = (const float*)d_in[6];
  const float* beta1 = (const float*)d_in[7];
  const float* g2    = (const float*)d_in[8];
  const float* beta2 = (const float*)d_in[9];
  const float* Wf1   = (const float*)d_in[10];
  const float* bf1   = (const float*)d_in[11];
  const float* Wf2   = (const float*)d_in[12];
  const float* bf2   = (const float*)d_in[13];

  char* ws = (char*)d_ws;
  unsigned short* wqkv_t = (unsigned short*)(ws);
  unsigned short* wout_t = (unsigned short*)(ws + 393216);
  unsigned short* wf1_t  = (unsigned short*)(ws + 524288);
  unsigned short* wf2_t  = (unsigned short*)(ws + 786432);
  size_t off = 1048576;
  unsigned short* h_n    = (unsigned short*)(ws + off); off += (size_t)8192 * 256 * 2;
  unsigned short* qkv    = (unsigned short*)(ws + off); off += (size_t)8192 * 768 * 2;
  unsigned short* vtb    = (unsigned short*)(ws + off); off += (size_t)1024 * 2048 * 2;
  unsigned short* attn_o = (unsigned short*)(ws + off); off += (size_t)8192 * 256 * 2;
  float*          h_mid  = (float*)(ws + off);          off += (size_t)8192 * 256 * 4;
  unsigned short* h2     = (unsigned short*)(ws + off); off += (size_t)8192 * 256 * 2;
  unsigned short* a1     = (unsigned short*)(ws + off); off += (size_t)8192 * 512 * 2;

  prep_weights<<<2048, 256, 0, stream>>>(Wqkv, Wout, Wf1, Wf2, wqkv_t, wout_t, wf1_t, wf2_t);
  ln_kernel<<<2048, 256, 0, stream>>>(h_in, g1, beta1, h_n);
  gemm_kernel<0, 256, 768><<<dim3(64, 12), 256, 0, stream>>>(h_n, wqkv_t, bqkv, nullptr, qkv);
  transpose_v<<<1024, 256, 0, stream>>>(qkv, vtb);
  attn_kernel<<<dim3(64, 4), 512, 0, stream>>>(qkv, vtb, adj, attn_o);
  gemm_kernel<1, 256, 256><<<dim3(64, 4), 256, 0, stream>>>(attn_o, wout_t, bout, h_in, h_mid);
  ln_kernel<<<2048, 256, 0, stream>>>(h_mid, g2, beta2, h2);
  gemm_kernel<2, 256, 512><<<dim3(64, 8), 256, 0, stream>>>(h2, wf1_t, bf1, nullptr, a1);
  gemm_kernel<1, 512, 256><<<dim3(64, 4), 256, 0, stream>>>(a1, wf2_t, bf2, h_mid, (float*)d_out);
}

// Round 4
// 197.829 us; speedup vs baseline: 1.2739x; 1.0091x over previous
//
#include <hip/hip_runtime.h>
#include <hip/hip_bf16.h>
#include <cstdint>
#include <cstddef>

typedef __bf16 bf16x8 __attribute__((ext_vector_type(8)));
typedef float f32x4 __attribute__((ext_vector_type(4)));
typedef float f32x16 __attribute__((ext_vector_type(16)));
typedef unsigned int u32x4 __attribute__((ext_vector_type(4)));

union U16x8 {
  u32x4 u;
  bf16x8 b;
  unsigned short s[8];
  ushort4 q[2];
};

__device__ __forceinline__ unsigned short f2bf(float f) {
  union { float f; unsigned u; } v;
  v.f = f;
  unsigned r = v.u + 0x7FFFu + ((v.u >> 16) & 1u);
  return (unsigned short)(r >> 16);
}

__device__ __forceinline__ unsigned pack2(float a, float b) {
  __hip_bfloat162 t = __float22bfloat162_rn(make_float2(a, b));
  return *reinterpret_cast<unsigned*>(&t);  // low16 = bf(a), high16 = bf(b)
}

// ---------------- weight prep: f32 -> bf16, transposed to [N][K] ----------------
__global__ __launch_bounds__(256) void prep_weights(
    const float* __restrict__ Wqkv, const float* __restrict__ Wout,
    const float* __restrict__ Wf1, const float* __restrict__ Wf2,
    unsigned short* __restrict__ qkv_t, unsigned short* __restrict__ out_t,
    unsigned short* __restrict__ f1_t, unsigned short* __restrict__ f2_t) {
  int i = blockIdx.x * 256 + threadIdx.x;
  if (i < 768 * 256) { int n = i >> 8, k = i & 255; qkv_t[i] = f2bf(Wqkv[k * 768 + n]); return; }
  i -= 768 * 256;
  if (i < 256 * 256) { int n = i >> 8, k = i & 255; out_t[i] = f2bf(Wout[k * 256 + n]); return; }
  i -= 256 * 256;
  if (i < 512 * 256) { int n = i >> 8, k = i & 255; f1_t[i] = f2bf(Wf1[k * 512 + n]); return; }
  i -= 512 * 256;
  if (i < 256 * 512) { int n = i >> 9, k = i & 511; f2_t[i] = f2bf(Wf2[k * 256 + n]); return; }
}

// ---------------- LayerNorm (f32 in -> bf16 out), 1 wave per 256-wide row ----------------
__global__ __launch_bounds__(256) void ln_kernel(
    const float* __restrict__ x, const float* __restrict__ gw, const float* __restrict__ bw,
    unsigned short* __restrict__ out) {
  const int row = blockIdx.x * 4 + (threadIdx.x >> 6);
  const int lane = threadIdx.x & 63;
  const float4 v = *reinterpret_cast<const float4*>(x + (size_t)row * 256 + lane * 4);
  float s = v.x + v.y + v.z + v.w;
  float s2 = v.x * v.x + v.y * v.y + v.z * v.z + v.w * v.w;
#pragma unroll
  for (int m = 1; m < 64; m <<= 1) {
    s += __shfl_xor(s, m);
    s2 += __shfl_xor(s2, m);
  }
  const float mean = s * (1.f / 256.f);
  const float var = s2 * (1.f / 256.f) - mean * mean;
  const float rstd = rsqrtf(var + 1e-5f);
  const float4 gg = *reinterpret_cast<const float4*>(gw + lane * 4);
  const float4 bb = *reinterpret_cast<const float4*>(bw + lane * 4);
  ushort4 o;
  o.x = f2bf((v.x - mean) * rstd * gg.x + bb.x);
  o.y = f2bf((v.y - mean) * rstd * gg.y + bb.y);
  o.z = f2bf((v.z - mean) * rstd * gg.z + bb.z);
  o.w = f2bf((v.w - mean) * rstd * gg.w + bb.w);
  *reinterpret_cast<ushort4*>(out + (size_t)row * 256 + lane * 4) = o;
}

// ---------------- direct-global MFMA GEMM: C[M][N] = A[M][K](bf16) @ Wt[N][K](bf16)^T ----------------
template <int EPI, int K, int N>
__global__ __launch_bounds__(256) void gemm_kernel(
    const unsigned short* __restrict__ A, const unsigned short* __restrict__ Wt,
    const float* __restrict__ bias, const float* __restrict__ res, void* __restrict__ outp) {
  const int w = threadIdx.x >> 6;
  const int lane = threadIdx.x & 63;
  const int l15 = lane & 15;
  const int g = lane >> 4;
  const int m0 = blockIdx.x * 128 + w * 32;
  const int n0 = blockIdx.y * 64;

  f32x4 acc[2][4];
#pragma unroll
  for (int mf = 0; mf < 2; ++mf)
#pragma unroll
    for (int nf = 0; nf < 4; ++nf) acc[mf][nf] = f32x4{0.f, 0.f, 0.f, 0.f};

#pragma unroll 4
  for (int kk = 0; kk < K / 32; ++kk) {
    U16x8 a[2], bfr[4];
#pragma unroll
    for (int mf = 0; mf < 2; ++mf)
      a[mf].u = *reinterpret_cast<const u32x4*>(A + (size_t)(m0 + mf * 16 + l15) * K + kk * 32 + g * 8);
#pragma unroll
    for (int nf = 0; nf < 4; ++nf)
      bfr[nf].u = *reinterpret_cast<const u32x4*>(Wt + (size_t)(n0 + nf * 16 + l15) * K + kk * 32 + g * 8);
#pragma unroll
    for (int mf = 0; mf < 2; ++mf)
#pragma unroll
      for (int nf = 0; nf < 4; ++nf)
        acc[mf][nf] = __builtin_amdgcn_mfma_f32_16x16x32_bf16(a[mf].b, bfr[nf].b, acc[mf][nf], 0, 0, 0);
  }

#pragma unroll
  for (int mf = 0; mf < 2; ++mf)
#pragma unroll
    for (int nf = 0; nf < 4; ++nf)
#pragma unroll
      for (int r = 0; r < 4; ++r) {
        const int m = m0 + mf * 16 + g * 4 + r;
        const int n = n0 + nf * 16 + l15;
        float v = acc[mf][nf][r] + bias[n];
        if constexpr (EPI == 1) {
          v += res[(size_t)m * 256 + n];
          reinterpret_cast<float*>(outp)[(size_t)m * 256 + n] = v;
        } else if constexpr (EPI == 2) {
          v = 0.5f * v * (1.0f + erff(v * 0.70710678118654752f));
          reinterpret_cast<unsigned short*>(outp)[(size_t)m * N + n] = f2bf(v);
        } else {
          reinterpret_cast<unsigned short*>(outp)[(size_t)m * N + n] = f2bf(v);
        }
      }
}

// ---------------- V transpose: qkv[:,512:768] (per b,h: [c][dk]) -> vt [b][h][dk][c] ----------------
__global__ __launch_bounds__(256) void transpose_v(
    const unsigned short* __restrict__ qkv, unsigned short* __restrict__ vt) {
  __shared__ unsigned short tile[64][40];
  const int t = threadIdx.x;
  const int ct = blockIdx.x & 31;
  const int h = (blockIdx.x >> 5) & 7;
  const int b = blockIdx.x >> 8;
  {
    const int c = t >> 2;
    const int dkb = (t & 3) * 8;
    U16x8 v;
    v.u = *reinterpret_cast<const u32x4*>(qkv + (size_t)(b * 2048 + ct * 64 + c) * 768 + 512 + h * 32 + dkb);
#pragma unroll
    for (int j = 0; j < 8; ++j) tile[c][dkb + j] = v.s[j];
  }
  __syncthreads();
  {
    const int dk = t >> 3;
    const int cb = (t & 7) * 8;
    U16x8 v;
#pragma unroll
    for (int j = 0; j < 8; ++j) v.s[j] = tile[cb + j][dk];
    *reinterpret_cast<u32x4*>(vt + (size_t)((b * 8 + h) * 32 + dk) * 2048 + ct * 64 + cb) = v.u;
  }
}

// ---------------- flash attention, 32x32 MFMA, in-register softmax, KV-split ----------------
// Block = (qtile32, b, head-group of 4). 8 waves: w&3 = head-in-group, w>>2 = kv half.
// S^T[k][q] = mfma32(K, Q^T): lane l31 = q, regs+hi = k (k = (r&3)+8*(r>>2)+4*hi).
// Softmax per-lane + one shfl_xor(32). P->bf16 B-frag via cvt_pk + lane^32 exchange.
// O^T[d][q] = mfma32(V^T, P). KV halves merged through LDS at the end.
__global__ __launch_bounds__(512) void attn_kernel(
    const unsigned short* __restrict__ qkv, const unsigned short* __restrict__ vt,
    const float* __restrict__ adj, unsigned short* __restrict__ out) {
  __shared__ __align__(16) float lds_o[4][32][36];  // [head][q][d] pad 36 (4-way max)
  __shared__ float lds_ml[4][2][32];
  const int w = threadIdx.x >> 6;
  const int lane = threadIdx.x & 63;
  const int l31 = lane & 31;
  const int hi = lane >> 5;
  const int hh = w & 3;
  const int kvh = w >> 2;
  const int q0 = blockIdx.x * 32;
  const int b = blockIdx.y;
  const int h = blockIdx.z * 4 + hh;
  const float scale = 0.17677669529663689f;  // 1/sqrt(32)

  // Q B-frags (persistent): B[kk=hi*8+j][q=l31] for dk blocks 0,1
  U16x8 qb[2];
#pragma unroll
  for (int d = 0; d < 2; ++d)
    qb[d].u = *reinterpret_cast<const u32x4*>(
        qkv + (size_t)(b * 2048 + q0 + l31) * 768 + h * 32 + d * 16 + hi * 8);

  f32x16 o;
#pragma unroll
  for (int i = 0; i < 16; ++i) o[i] = 0.f;
  float mrun = -1e30f, lrun = 0.f;

  const float* aptr = adj + ((size_t)(b * 2048 + q0 + l31)) * 2048 + kvh * 1024 + hi * 4;
  const unsigned short* kptr =
      qkv + ((size_t)(b * 2048 + kvh * 1024 + l31)) * 768 + 256 + h * 32 + hi * 8;
  const unsigned short* vptr =
      vt + ((size_t)((b * 8 + h) * 32 + l31)) * 2048 + kvh * 1024 + hi * 8;

  // adj double-buffered (the only cold-HBM stream); K/V are L2-resident
  f32x4 adjv[2][4];
#pragma unroll
  for (int G = 0; G < 4; ++G) adjv[0][G] = *reinterpret_cast<const f32x4*>(aptr + G * 8);

#pragma unroll 2
  for (int t = 0; t < 32; ++t) {
    const int cur = t & 1, nxt = cur ^ 1;
    // prefetch next adj tile (dist 1)
    if (t < 31) {
      const float* ap = aptr + (t + 1) * 32;
#pragma unroll
      for (int G = 0; G < 4; ++G) adjv[nxt][G] = *reinterpret_cast<const f32x4*>(ap + G * 8);
    }
    // K A-frags: A[k=l31][kk=hi*8+j] for dk blocks 0,1
    U16x8 kb[2];
#pragma unroll
    for (int d = 0; d < 2; ++d)
      kb[d].u = *reinterpret_cast<const u32x4*>(kptr + (size_t)t * 32 * 768 + d * 16);
    // V A-frags: A[d=l31][kk] for k-blocks 0,1 of this 32-k tile
    U16x8 vb[2];
#pragma unroll
    for (int kb2 = 0; kb2 < 2; ++kb2)
      vb[kb2].u = *reinterpret_cast<const u32x4*>(vptr + t * 32 + kb2 * 16);

    // S^T = K·Q^T (accumulate over 2 dk-blocks)
    f32x16 s;
    {
      f32x16 z;
#pragma unroll
      for (int i = 0; i < 16; ++i) z[i] = 0.f;
      s = __builtin_amdgcn_mfma_f32_32x32x16_bf16(kb[0].b, qb[0].b, z, 0, 0, 0);
      s = __builtin_amdgcn_mfma_f32_32x32x16_bf16(kb[1].b, qb[1].b, s, 0, 0, 0);
    }

    // scale + adj: reg G*4+r <-> k = 8G + 4hi + r
#pragma unroll
    for (int G = 0; G < 4; ++G)
#pragma unroll
      for (int r = 0; r < 4; ++r)
        s[G * 4 + r] = fmaf(s[G * 4 + r], scale, adjv[cur][G][r]);

    // per-q max: 16 lane-local + partner half
    float mx = s[0];
#pragma unroll
    for (int i = 1; i < 16; ++i) mx = fmaxf(mx, s[i]);
    mx = fmaxf(mx, __shfl_xor(mx, 32));

    // defer-max (T13)
    if (!__all(mx <= mrun + 8.f)) {
      const float mnew = fmaxf(mrun, mx);
      const float alpha = __expf(mrun - mnew);
      mrun = mnew;
      lrun *= alpha;
#pragma unroll
      for (int i = 0; i < 16; ++i) o[i] *= alpha;
    }

    float rs = 0.f;
#pragma unroll
    for (int i = 0; i < 16; ++i) {
      const float p = __expf(s[i] - mrun);
      s[i] = p;
      rs += p;
    }
    rs += __shfl_xor(rs, 32);
    lrun += rs;

    // pack P to bf16 words: Pw[G][p] = ks {8G+4hi+2p, +1}
    unsigned Pw[4][2];
#pragma unroll
    for (int G = 0; G < 4; ++G) {
      Pw[G][0] = pack2(s[4 * G], s[4 * G + 1]);
      Pw[G][1] = pack2(s[4 * G + 2], s[4 * G + 3]);
    }
    // lane^32 exchange -> PV B-frags: B[kk=hi*8+j][q=l31], k-blocks kb2=0,1
    U16x8 pb[2];
#pragma unroll
    for (int kb2 = 0; kb2 < 2; ++kb2) {
#pragma unroll
      for (int p = 0; p < 2; ++p) {
        const unsigned a = Pw[2 * kb2][p], c = Pw[2 * kb2 + 1][p];
        const unsigned send = hi ? a : c;
        const unsigned recv = (unsigned)__shfl_xor((int)send, 32);
        pb[kb2].u[p] = hi ? recv : a;       // word j=2p,2p+1
        pb[kb2].u[2 + p] = hi ? c : recv;   // word j=4+2p,4+2p+1
      }
    }

    // PV: O^T += V^T · P
#pragma unroll
    for (int kb2 = 0; kb2 < 2; ++kb2)
      o = __builtin_amdgcn_mfma_f32_32x32x16_bf16(vb[kb2].b, pb[kb2].b, o, 0, 0, 0);
  }

  // merge the two KV halves through LDS
  if (kvh == 1) {
#pragma unroll
    for (int G = 0; G < 4; ++G) {
      f32x4 v4;
#pragma unroll
      for (int r = 0; r < 4; ++r) v4[r] = o[4 * G + r];
      *reinterpret_cast<f32x4*>(&lds_o[hh][l31][8 * G + 4 * hi]) = v4;
    }
    if (hi == 0) {
      lds_ml[hh][0][l31] = mrun;
      lds_ml[hh][1][l31] = lrun;
    }
  }
  __syncthreads();
  if (kvh == 0) {
    const float m1 = lds_ml[hh][0][l31];
    const float l1 = lds_ml[hh][1][l31];
    const float mm = fmaxf(mrun, m1);
    const float a0 = __expf(mrun - mm);
    const float a1 = __expf(m1 - mm);
    const float linv = 1.f / (a0 * lrun + a1 * l1);
#pragma unroll
    for (int G = 0; G < 4; ++G) {
      const f32x4 o1 = *reinterpret_cast<const f32x4*>(&lds_o[hh][l31][8 * G + 4 * hi]);
      ushort4 st;
      st.x = f2bf((a0 * o[4 * G + 0] + a1 * o1[0]) * linv);
      st.y = f2bf((a0 * o[4 * G + 1] + a1 * o1[1]) * linv);
      st.z = f2bf((a0 * o[4 * G + 2] + a1 * o1[2]) * linv);
      st.w = f2bf((a0 * o[4 * G + 3] + a1 * o1[3]) * linv);
      *reinterpret_cast<ushort4*>(out + (size_t)(b * 2048 + q0 + l31) * 256 + h * 32 + 8 * G + 4 * hi) = st;
    }
  }
}

extern "C" void kernel_launch(void* const* d_in, const int* in_sizes, int n_in,
                              void* d_out, int out_size, void* d_ws, size_t ws_size,
                              hipStream_t stream) {
  const float* h_in  = (const float*)d_in[0];
  const float* adj   = (const float*)d_in[1];
  const float* Wqkv  = (const float*)d_in[2];
  const float* bqkv  = (const float*)d_in[3];
  const float* Wout  = (const float*)d_in[4];
  const float* bout  = (const float*)d_in[5];
  const float* g1    = (const float*)d_in[6];
  const float* beta1 = (const float*)d_in[7];
  const float* g2    = (const float*)d_in[8];
  const float* beta2 = (const float*)d_in[9];
  const float* Wf1   = (const float*)d_in[10];
  const float* bf1   = (const float*)d_in[11];
  const float* Wf2   = (const float*)d_in[12];
  const float* bf2   = (const float*)d_in[13];

  char* ws = (char*)d_ws;
  unsigned short* wqkv_t = (unsigned short*)(ws);
  unsigned short* wout_t = (unsigned short*)(ws + 393216);
  unsigned short* wf1_t  = (unsigned short*)(ws + 524288);
  unsigned short* wf2_t  = (unsigned short*)(ws + 786432);
  size_t off = 1048576;
  unsigned short* h_n    = (unsigned short*)(ws + off); off += (size_t)8192 * 256 * 2;
  unsigned short* qkv    = (unsigned short*)(ws + off); off += (size_t)8192 * 768 * 2;
  unsigned short* vtb    = (unsigned short*)(ws + off); off += (size_t)1024 * 2048 * 2;
  unsigned short* attn_o = (unsigned short*)(ws + off); off += (size_t)8192 * 256 * 2;
  float*          h_mid  = (float*)(ws + off);          off += (size_t)8192 * 256 * 4;
  unsigned short* h2     = (unsigned short*)(ws + off); off += (size_t)8192 * 256 * 2;
  unsigned short* a1     = (unsigned short*)(ws + off); off += (size_t)8192 * 512 * 2;

  prep_weights<<<2048, 256, 0, stream>>>(Wqkv, Wout, Wf1, Wf2, wqkv_t, wout_t, wf1_t, wf2_t);
  ln_kernel<<<2048, 256, 0, stream>>>(h_in, g1, beta1, h_n);
  gemm_kernel<0, 256, 768><<<dim3(64, 12), 256, 0, stream>>>(h_n, wqkv_t, bqkv, nullptr, qkv);
  transpose_v<<<1024, 256, 0, stream>>>(qkv, vtb);
  attn_kernel<<<dim3(64, 4, 2), 512, 0, stream>>>(qkv, vtb, adj, attn_o);
  gemm_kernel<1, 256, 256><<<dim3(64, 4), 256, 0, stream>>>(attn_o, wout_t, bout, h_in, h_mid);
  ln_kernel<<<2048, 256, 0, stream>>>(h_mid, g2, beta2, h2);
  gemm_kernel<2, 256, 512><<<dim3(64, 8), 256, 0, stream>>>(h2, wf1_t, bf1, nullptr, a1);
  gemm_kernel<1, 512, 256><<<dim3(64, 4), 256, 0, stream>>>(a1, wf2_t, bf2, h_mid, (float*)d_out);
}

// Round 5
// 170.930 us; speedup vs baseline: 1.4743x; 1.1574x over previous
//
#include <hip/hip_runtime.h>
#include <hip/hip_bf16.h>
#include <cstdint>
#include <cstddef>

typedef __bf16 bf16x8 __attribute__((ext_vector_type(8)));
typedef float f32x4 __attribute__((ext_vector_type(4)));
typedef float f32x16 __attribute__((ext_vector_type(16)));
typedef unsigned int u32x4 __attribute__((ext_vector_type(4)));

union U16x8 {
  u32x4 u;
  bf16x8 b;
  unsigned short s[8];
  ushort4 q[2];
};

__device__ __forceinline__ unsigned short f2bf(float f) {
  union { float f; unsigned u; } v;
  v.f = f;
  unsigned r = v.u + 0x7FFFu + ((v.u >> 16) & 1u);
  return (unsigned short)(r >> 16);
}

__device__ __forceinline__ unsigned pack2(float a, float b) {
  __hip_bfloat162 t = __float22bfloat162_rn(make_float2(a, b));
  return *reinterpret_cast<unsigned*>(&t);  // low16 = bf(a), high16 = bf(b)
}

// ---------------- weight prep: f32 -> bf16, transposed to [N][K] ----------------
__global__ __launch_bounds__(256) void prep_weights(
    const float* __restrict__ Wqkv, const float* __restrict__ Wout,
    const float* __restrict__ Wf1, const float* __restrict__ Wf2,
    unsigned short* __restrict__ qkv_t, unsigned short* __restrict__ out_t,
    unsigned short* __restrict__ f1_t, unsigned short* __restrict__ f2_t) {
  int i = blockIdx.x * 256 + threadIdx.x;
  if (i < 768 * 256) { int n = i >> 8, k = i & 255; qkv_t[i] = f2bf(Wqkv[k * 768 + n]); return; }
  i -= 768 * 256;
  if (i < 256 * 256) { int n = i >> 8, k = i & 255; out_t[i] = f2bf(Wout[k * 256 + n]); return; }
  i -= 256 * 256;
  if (i < 512 * 256) { int n = i >> 8, k = i & 255; f1_t[i] = f2bf(Wf1[k * 512 + n]); return; }
  i -= 512 * 256;
  if (i < 256 * 512) { int n = i >> 9, k = i & 511; f2_t[i] = f2bf(Wf2[k * 256 + n]); return; }
}

// ---------------- LayerNorm (f32 in -> bf16 out), 1 wave per 256-wide row ----------------
__global__ __launch_bounds__(256) void ln_kernel(
    const float* __restrict__ x, const float* __restrict__ gw, const float* __restrict__ bw,
    unsigned short* __restrict__ out) {
  const int row = blockIdx.x * 4 + (threadIdx.x >> 6);
  const int lane = threadIdx.x & 63;
  const float4 v = *reinterpret_cast<const float4*>(x + (size_t)row * 256 + lane * 4);
  float s = v.x + v.y + v.z + v.w;
  float s2 = v.x * v.x + v.y * v.y + v.z * v.z + v.w * v.w;
#pragma unroll
  for (int m = 1; m < 64; m <<= 1) {
    s += __shfl_xor(s, m);
    s2 += __shfl_xor(s2, m);
  }
  const float mean = s * (1.f / 256.f);
  const float var = s2 * (1.f / 256.f) - mean * mean;
  const float rstd = rsqrtf(var + 1e-5f);
  const float4 gg = *reinterpret_cast<const float4*>(gw + lane * 4);
  const float4 bb = *reinterpret_cast<const float4*>(bw + lane * 4);
  ushort4 o;
  o.x = f2bf((v.x - mean) * rstd * gg.x + bb.x);
  o.y = f2bf((v.y - mean) * rstd * gg.y + bb.y);
  o.z = f2bf((v.z - mean) * rstd * gg.z + bb.z);
  o.w = f2bf((v.w - mean) * rstd * gg.w + bb.w);
  *reinterpret_cast<ushort4*>(out + (size_t)row * 256 + lane * 4) = o;
}

// ---------------- direct-global MFMA GEMM: C[M][N] = A[M][K](bf16) @ Wt[N][K](bf16)^T ----------------
template <int EPI, int K, int N>
__global__ __launch_bounds__(256) void gemm_kernel(
    const unsigned short* __restrict__ A, const unsigned short* __restrict__ Wt,
    const float* __restrict__ bias, const float* __restrict__ res, void* __restrict__ outp) {
  const int w = threadIdx.x >> 6;
  const int lane = threadIdx.x & 63;
  const int l15 = lane & 15;
  const int g = lane >> 4;
  const int m0 = blockIdx.x * 128 + w * 32;
  const int n0 = blockIdx.y * 64;

  f32x4 acc[2][4];
#pragma unroll
  for (int mf = 0; mf < 2; ++mf)
#pragma unroll
    for (int nf = 0; nf < 4; ++nf) acc[mf][nf] = f32x4{0.f, 0.f, 0.f, 0.f};

#pragma unroll 4
  for (int kk = 0; kk < K / 32; ++kk) {
    U16x8 a[2], bfr[4];
#pragma unroll
    for (int mf = 0; mf < 2; ++mf)
      a[mf].u = *reinterpret_cast<const u32x4*>(A + (size_t)(m0 + mf * 16 + l15) * K + kk * 32 + g * 8);
#pragma unroll
    for (int nf = 0; nf < 4; ++nf)
      bfr[nf].u = *reinterpret_cast<const u32x4*>(Wt + (size_t)(n0 + nf * 16 + l15) * K + kk * 32 + g * 8);
#pragma unroll
    for (int mf = 0; mf < 2; ++mf)
#pragma unroll
      for (int nf = 0; nf < 4; ++nf)
        acc[mf][nf] = __builtin_amdgcn_mfma_f32_16x16x32_bf16(a[mf].b, bfr[nf].b, acc[mf][nf], 0, 0, 0);
  }

#pragma unroll
  for (int mf = 0; mf < 2; ++mf)
#pragma unroll
    for (int nf = 0; nf < 4; ++nf)
#pragma unroll
      for (int r = 0; r < 4; ++r) {
        const int m = m0 + mf * 16 + g * 4 + r;
        const int n = n0 + nf * 16 + l15;
        float v = acc[mf][nf][r] + bias[n];
        if constexpr (EPI == 1) {
          v += res[(size_t)m * 256 + n];
          reinterpret_cast<float*>(outp)[(size_t)m * 256 + n] = v;
        } else if constexpr (EPI == 2) {
          v = 0.5f * v * (1.0f + erff(v * 0.70710678118654752f));
          reinterpret_cast<unsigned short*>(outp)[(size_t)m * N + n] = f2bf(v);
        } else {
          reinterpret_cast<unsigned short*>(outp)[(size_t)m * N + n] = f2bf(v);
        }
      }
}

// ---------------- V transpose: qkv[:,512:768] (per b,h: [c][dk]) -> vt [b][h][dk][c] ----------------
__global__ __launch_bounds__(256) void transpose_v(
    const unsigned short* __restrict__ qkv, unsigned short* __restrict__ vt) {
  __shared__ unsigned short tile[64][40];
  const int t = threadIdx.x;
  const int ct = blockIdx.x & 31;
  const int h = (blockIdx.x >> 5) & 7;
  const int b = blockIdx.x >> 8;
  {
    const int c = t >> 2;
    const int dkb = (t & 3) * 8;
    U16x8 v;
    v.u = *reinterpret_cast<const u32x4*>(qkv + (size_t)(b * 2048 + ct * 64 + c) * 768 + 512 + h * 32 + dkb);
#pragma unroll
    for (int j = 0; j < 8; ++j) tile[c][dkb + j] = v.s[j];
  }
  __syncthreads();
  {
    const int dk = t >> 3;
    const int cb = (t & 7) * 8;
    U16x8 v;
#pragma unroll
    for (int j = 0; j < 8; ++j) v.s[j] = tile[cb + j][dk];
    *reinterpret_cast<u32x4*>(vt + (size_t)((b * 8 + h) * 32 + dk) * 2048 + ct * 64 + cb) = v.u;
  }
}

// ---------------- flash attention: adj staged via async global_load_lds DMA ----------------
// Block = (qtile32, b); 8 waves = 8 heads sharing the adj tile.
// S^T[k][q] = mfma32(K, Q^T): lane l31 = q; regs+hi = k. Softmax lane-local + shfl_xor(32).
// adj tile (32q x 128k f32, rows padded to 132 f32) triple-buffered in LDS; DMA'd with
// width-4 global_load_lds (coalesced 256B per instr), counted vmcnt + raw s_barrier
// (NOT __syncthreads -- that drains vmcnt(0) and kills the prefetch depth).
__global__ __launch_bounds__(512) void attn_kernel(
    const unsigned short* __restrict__ qkv, const unsigned short* __restrict__ vt,
    const float* __restrict__ adj, unsigned short* __restrict__ out) {
  __shared__ __align__(16) float adj_lds[3][32 * 132];
  const int w = threadIdx.x >> 6;   // head
  const int lane = threadIdx.x & 63;
  const int l31 = lane & 31;
  const int hi = lane >> 5;
  const int q0 = blockIdx.x * 32;
  const int b = blockIdx.y;
  const int h = w;
  const float scale = 0.17677669529663689f;  // 1/sqrt(32)

  // wave w stages q-rows 4w..4w+3; lane supplies col t*128 + half*64 + lane
  const float* agbase = adj + (size_t)(b * 2048 + q0 + 4 * w) * 2048 + lane;

  // Q B-frags (persistent): B[kk=hi*8+j][q=l31] for dk halves 0,1
  U16x8 qb[2];
#pragma unroll
  for (int d = 0; d < 2; ++d)
    qb[d].u = *reinterpret_cast<const u32x4*>(
        qkv + (size_t)(b * 2048 + q0 + l31) * 768 + h * 32 + d * 16 + hi * 8);

  const unsigned short* kptr = qkv + (size_t)(b * 2048 + l31) * 768 + 256 + h * 32 + hi * 8;
  const unsigned short* vptr = vt + (size_t)((b * 8 + h) * 32 + l31) * 2048 + hi * 8;

  f32x16 o;
#pragma unroll
  for (int i = 0; i < 16; ++i) o[i] = 0.f;
  float mrun = -1e30f, lrun = 0.f;

  // prologue: DMA tiles 0,1,2 (8 dword-DMAs per wave per tile)
#pragma unroll
  for (int pt = 0; pt < 3; ++pt)
#pragma unroll
    for (int r = 0; r < 4; ++r)
#pragma unroll
      for (int half = 0; half < 2; ++half)
        __builtin_amdgcn_global_load_lds(
            (const __attribute__((address_space(1))) unsigned int*)(agbase + (size_t)r * 2048 + pt * 128 + half * 64),
            (__attribute__((address_space(3))) unsigned int*)(&adj_lds[pt][(4 * w + r) * 132 + half * 64]),
            4, 0, 0);

#pragma unroll 1
  for (int t = 0; t < 16; ++t) {
    const float* buf = adj_lds[t % 3];
    // stage(t) done when <= 16 of our DMA loads outstanding (t+1,t+2 in flight)
    if (t < 14)       asm volatile("s_waitcnt vmcnt(16)" ::: "memory");
    else if (t == 14) asm volatile("s_waitcnt vmcnt(8)" ::: "memory");
    else              asm volatile("s_waitcnt vmcnt(0)" ::: "memory");
    __builtin_amdgcn_s_barrier();
    __builtin_amdgcn_sched_barrier(0);

    // ---- QK^T: S^T[k][q], 4 k-subtiles of 32 ----
    f32x16 s[4];
#pragma unroll
    for (int sub = 0; sub < 4; ++sub) {
      const unsigned short* kp = kptr + (size_t)(t * 128 + sub * 32) * 768;
      U16x8 kb0, kb1;
      kb0.u = *reinterpret_cast<const u32x4*>(kp);
      kb1.u = *reinterpret_cast<const u32x4*>(kp + 16);
      f32x16 z;
#pragma unroll
      for (int i = 0; i < 16; ++i) z[i] = 0.f;
      s[sub] = __builtin_amdgcn_mfma_f32_32x32x16_bf16(kb0.b, qb[0].b, z, 0, 0, 0);
      s[sub] = __builtin_amdgcn_mfma_f32_32x32x16_bf16(kb1.b, qb[1].b, s[sub], 0, 0, 0);
    }

    // ---- scale + adj from LDS (reg 4G+r <-> k = sub*32 + 8G + 4hi + r) ----
#pragma unroll
    for (int sub = 0; sub < 4; ++sub)
#pragma unroll
      for (int G = 0; G < 4; ++G) {
        const f32x4 av = *reinterpret_cast<const f32x4*>(&buf[l31 * 132 + sub * 32 + G * 8 + hi * 4]);
#pragma unroll
        for (int r = 0; r < 4; ++r)
          s[sub][G * 4 + r] = fmaf(s[sub][G * 4 + r], scale, av[r]);
      }

    // ---- online softmax (per-lane rows + one cross-half reduce) ----
    float mx = s[0][0];
#pragma unroll
    for (int sub = 0; sub < 4; ++sub)
#pragma unroll
      for (int i = 0; i < 16; ++i) mx = fmaxf(mx, s[sub][i]);
    mx = fmaxf(mx, __shfl_xor(mx, 32));

    if (!__all(mx <= mrun + 8.f)) {  // defer-max (T13)
      const float mnew = fmaxf(mrun, mx);
      const float alpha = __expf(mrun - mnew);
      mrun = mnew;
      lrun *= alpha;
#pragma unroll
      for (int i = 0; i < 16; ++i) o[i] *= alpha;
    }

    float rs = 0.f;
#pragma unroll
    for (int sub = 0; sub < 4; ++sub)
#pragma unroll
      for (int i = 0; i < 16; ++i) {
        const float p = __expf(s[sub][i] - mrun);
        s[sub][i] = p;
        rs += p;
      }
    rs += __shfl_xor(rs, 32);
    lrun += rs;

    // ---- pack P -> bf16, lane^32 exchange, PV ----
#pragma unroll
    for (int sub = 0; sub < 4; ++sub) {
      unsigned Pw[4][2];
#pragma unroll
      for (int G = 0; G < 4; ++G) {
        Pw[G][0] = pack2(s[sub][4 * G], s[sub][4 * G + 1]);
        Pw[G][1] = pack2(s[sub][4 * G + 2], s[sub][4 * G + 3]);
      }
      U16x8 pb[2];
#pragma unroll
      for (int kb2 = 0; kb2 < 2; ++kb2) {
#pragma unroll
        for (int p = 0; p < 2; ++p) {
          const unsigned a = Pw[2 * kb2][p], c = Pw[2 * kb2 + 1][p];
          const unsigned send = hi ? a : c;
          const unsigned recv = (unsigned)__shfl_xor((int)send, 32);
          pb[kb2].u[p] = hi ? recv : a;
          pb[kb2].u[2 + p] = hi ? c : recv;
        }
      }
      U16x8 vb0, vb1;
      vb0.u = *reinterpret_cast<const u32x4*>(vptr + t * 128 + sub * 32);
      vb1.u = *reinterpret_cast<const u32x4*>(vptr + t * 128 + sub * 32 + 16);
      o = __builtin_amdgcn_mfma_f32_32x32x16_bf16(vb0.b, pb[0].b, o, 0, 0, 0);
      o = __builtin_amdgcn_mfma_f32_32x32x16_bf16(vb1.b, pb[1].b, o, 0, 0, 0);
    }

    // all our LDS reads done; let everyone pass, then DMA-overwrite this buffer
    asm volatile("s_waitcnt lgkmcnt(0)" ::: "memory");
    __builtin_amdgcn_s_barrier();
    __builtin_amdgcn_sched_barrier(0);
    if (t + 3 < 16) {
      float* nb = adj_lds[t % 3];
#pragma unroll
      for (int r = 0; r < 4; ++r)
#pragma unroll
        for (int half = 0; half < 2; ++half)
          __builtin_amdgcn_global_load_lds(
              (const __attribute__((address_space(1))) unsigned int*)(agbase + (size_t)r * 2048 + (t + 3) * 128 + half * 64),
              (__attribute__((address_space(3))) unsigned int*)(nb + (4 * w + r) * 132 + half * 64),
              4, 0, 0);
    }
  }

  // ---- epilogue: normalize + store (o reg 4G+r <-> d = 8G + 4hi + r) ----
  const float linv = 1.0f / lrun;
#pragma unroll
  for (int G = 0; G < 4; ++G) {
    ushort4 st;
    st.x = f2bf(o[4 * G + 0] * linv);
    st.y = f2bf(o[4 * G + 1] * linv);
    st.z = f2bf(o[4 * G + 2] * linv);
    st.w = f2bf(o[4 * G + 3] * linv);
    *reinterpret_cast<ushort4*>(out + (size_t)(b * 2048 + q0 + l31) * 256 + h * 32 + G * 8 + hi * 4) = st;
  }
}

extern "C" void kernel_launch(void* const* d_in, const int* in_sizes, int n_in,
                              void* d_out, int out_size, void* d_ws, size_t ws_size,
                              hipStream_t stream) {
  const float* h_in  = (const float*)d_in[0];
  const float* adj   = (const float*)d_in[1];
  const float* Wqkv  = (const float*)d_in[2];
  const float* bqkv  = (const float*)d_in[3];
  const float* Wout  = (const float*)d_in[4];
  const float* bout  = (const float*)d_in[5];
  const float* g1    = (const float*)d_in[6];
  const float* beta1 = (const float*)d_in[7];
  const float* g2    = (const float*)d_in[8];
  const float* beta2 = (const float*)d_in[9];
  const float* Wf1   = (const float*)d_in[10];
  const float* bf1   = (const float*)d_in[11];
  const float* Wf2   = (const float*)d_in[12];
  const float* bf2   = (const float*)d_in[13];

  char* ws = (char*)d_ws;
  unsigned short* wqkv_t = (unsigned short*)(ws);
  unsigned short* wout_t = (unsigned short*)(ws + 393216);
  unsigned short* wf1_t  = (unsigned short*)(ws + 524288);
  unsigned short* wf2_t  = (unsigned short*)(ws + 786432);
  size_t off = 1048576;
  unsigned short* h_n    = (unsigned short*)(ws + off); off += (size_t)8192 * 256 * 2;
  unsigned short* qkv    = (unsigned short*)(ws + off); off += (size_t)8192 * 768 * 2;
  unsigned short* vtb    = (unsigned short*)(ws + off); off += (size_t)1024 * 2048 * 2;
  unsigned short* attn_o = (unsigned short*)(ws + off); off += (size_t)8192 * 256 * 2;
  float*          h_mid  = (float*)(ws + off);          off += (size_t)8192 * 256 * 4;
  unsigned short* h2     = (unsigned short*)(ws + off); off += (size_t)8192 * 256 * 2;
  unsigned short* a1     = (unsigned short*)(ws + off); off += (size_t)8192 * 512 * 2;

  prep_weights<<<2048, 256, 0, stream>>>(Wqkv, Wout, Wf1, Wf2, wqkv_t, wout_t, wf1_t, wf2_t);
  ln_kernel<<<2048, 256, 0, stream>>>(h_in, g1, beta1, h_n);
  gemm_kernel<0, 256, 768><<<dim3(64, 12), 256, 0, stream>>>(h_n, wqkv_t, bqkv, nullptr, qkv);
  transpose_v<<<1024, 256, 0, stream>>>(qkv, vtb);
  attn_kernel<<<dim3(64, 4), 512, 0, stream>>>(qkv, vtb, adj, attn_o);
  gemm_kernel<1, 256, 256><<<dim3(64, 4), 256, 0, stream>>>(attn_o, wout_t, bout, h_in, h_mid);
  ln_kernel<<<2048, 256, 0, stream>>>(h_mid, g2, beta2, h2);
  gemm_kernel<2, 256, 512><<<dim3(64, 8), 256, 0, stream>>>(h2, wf1_t, bf1, nullptr, a1);
  gemm_kernel<1, 512, 256><<<dim3(64, 4), 256, 0, stream>>>(a1, wf2_t, bf2, h_mid, (float*)d_out);
}